// Round 1
// baseline (172.805 us; speedup 1.0000x reference)
//
#include <hip/hip_runtime.h>
#include <hip/hip_bf16.h>

// reference(x) is a 2-level Haar DWT followed by its exact inverse:
//   dwt2 -> dwt2(ll1) -> (reshape/permute, immediately undone) -> idwt2 -> idwt2
// Each idwt2 exactly inverts the matching dwt2 (orthogonal Haar butterfly:
// a' = 0.25*[(a+b+c+d)-(c+d-a-b)-(b+d-a-c)+(a+d-b-c)] = a, etc.).
// Hence reference(x) == x up to fp32 rounding (~1e-6), far below the 1.08e-1
// harness threshold. Optimal kernel = D2D copy: 96 MiB in + 96 MiB out.

extern "C" void kernel_launch(void* const* d_in, const int* in_sizes, int n_in,
                              void* d_out, int out_size, void* d_ws, size_t ws_size,
                              hipStream_t stream) {
    const float* x = (const float*)d_in[0];
    float* out = (float*)d_out;
    size_t nbytes = (size_t)out_size * sizeof(float);  // 32*3*512*512 floats
    hipMemcpyAsync(out, x, nbytes, hipMemcpyDeviceToDevice, stream);
}

// Round 2
// 169.296 us; speedup vs baseline: 1.0207x; 1.0207x over previous
//
#include <hip/hip_runtime.h>
#include <hip/hip_bf16.h>

// reference(x) is a 2-level Haar DWT followed by its exact inverse:
//   dwt2 -> dwt2(ll1) -> (permute, immediately undone) -> idwt2 -> idwt2
// The Haar butterfly is orthogonal and exactly inverted, so reference(x) == x
// up to fp32 rounding (verified: absmax 0.0156 << 0.108 threshold).
// Optimal kernel = copy. hipMemcpyAsync measured 173 us (SDMA/blit path);
// a float4 shader copy should hit the ~6.7 TB/s fill-kernel ceiling: ~32 us.

__global__ __launch_bounds__(256) void copy_f4(const float4* __restrict__ src,
                                               float4* __restrict__ dst,
                                               int n4) {
    int i = blockIdx.x * 256 + threadIdx.x;
    if (i < n4) dst[i] = src[i];
}

extern "C" void kernel_launch(void* const* d_in, const int* in_sizes, int n_in,
                              void* d_out, int out_size, void* d_ws, size_t ws_size,
                              hipStream_t stream) {
    const float4* x = (const float4*)d_in[0];
    float4* out = (float4*)d_out;
    int n4 = out_size / 4;  // 25,165,824 / 4 = 6,291,456 float4s (exact)
    int blocks = (n4 + 255) / 256;  // 24,576
    copy_f4<<<blocks, 256, 0, stream>>>(x, out, n4);
}